// Round 9
// baseline (382.500 us; speedup 1.0000x reference)
//
#include <hip/hip_runtime.h>
#include <hip/hip_fp16.h>
#include <math.h>

// R14: 2-pair interleave per wave (ILP x2 at constant occupancy).
// R13 accounting: VALU issue = 2000 instr/pair * 2cyc * 65 pairs/CU = 108us
// = measured 49% of 223us; the rest is dependency-chain stall (serial step-2
// recurrence, shfl latency, mem waits) with only ~3 waves/SIMD. Fix: each
// wave runs TWO adjacent frame-pairs (4 frames) interleaved in registers:
//  - every stall slot gets a second independent chain (ILP x2)
//  - step-2 twiddle chain / stage twiddles / window are lane-only ->
//    computed ONCE, applied to both pairs
//  - frames 4w..4w+3 share the x halo: 28 chunks, not 2x20 (-30% VMEM)
// TPB 512->256 (4 waves, 8 pairs), FB=16 unchanged; LDS/write-out/fixup
// machinery identical to R13 (verified). launch_bounds(256,3) for VGPR room.
// Four-step FFT per pair (verified): 1024 = 16(in-reg) x 64(cross-lane);
// step1 per-lane 16pt DFT; step2 W1024^(l*k2); step3 6x radix-2 shfl_xor;
// lane l reg k2 = X[k2+16*brev6(l)]; untangle partner shfl_xor(reg 16-k2,63).
// Carries: two-for-one real FFT, zero-frame direct store, tightened fixup
// predicate (|im|<TAU && re<TAU), poly atan2, f64 fixup, fp16 staging,
// group-padded conflict-free result buffer.
// x: (32,1,262144) fp32; basis: (1026,1,1024) fp32.
// out: mag (32,513,1029) ++ angle (32,513,1029) fp32 flat.

#define NFFT     1024
#define STRIDE_  256
#define CUTOFF_  513
#define NFRAMES  1029
#define BATCH_   32
#define XLEN     262144
#define FB       16           // frames per block (8 pairs; 2 pairs/wave)
#define TPB      256
#define NTILES   65           // ceil(1029/16)
#define RSTRIDE  (FB + 1)     // 17
#define RESSZ    8800         // >= 512*17 + 32*2 + 15
#define QCAP     256          // expected ~25 used/block
#define TAU      0.05f
#define PI_F     3.14159265358979323846f
#define PIH_F    1.57079632679489661923f
#define TWO_PI   6.28318530717958647692f

// Group-padded result index: lane stride across f-groups = 548B = 137 dwords
// == 9 mod 32 -> conflict-free scatter (2 lanes/bank).
__device__ __forceinline__ int ridx(int f, int tt) {
    return f * RSTRIDE + ((f >> 4) << 1) + tt;
}

// Fast atan2: deg-7 minimax atan on [0,1] + quadrant logic. Max err ~1e-5 rad.
// mx==0 -> NaN, but such bins satisfy the queue predicate -> overwritten.
__device__ __forceinline__ float fast_atan2(float y, float x) {
    float ax = fabsf(x), ay = fabsf(y);
    float mx = fmaxf(ax, ay), mn = fminf(ax, ay);
    float a  = mn * __builtin_amdgcn_rcpf(mx);
    float s  = a * a;
    float r  = a * (0.9998660f + s * (-0.3302995f + s * (0.1801410f + s * (-0.0851330f))));
    if (ay > ax) r = PIH_F - r;
    if (x < 0.0f) r = PI_F - r;
    return copysignf(r, y);
}

// One cross-lane DIF radix-2 stage. Low lane: a+b. High lane: (b-a)*W.
#define XSTAGE(DIST, TC, TS) do {                        \
    float br_ = __shfl_xor(ar, DIST, 64);                \
    float bi_ = __shfl_xor(ai, DIST, 64);                \
    float dr_ = (lane & DIST) ? (br_ - ar) : (ar + br_); \
    float di_ = (lane & DIST) ? (bi_ - ai) : (ai + bi_); \
    ar = dr_ * (TC) - di_ * (TS);                        \
    ai = dr_ * (TS) + di_ * (TC);                        \
} while (0)

__global__ __launch_bounds__(TPB, 3) void stft_fft_kernel(
    const float* __restrict__ x, const float* __restrict__ basis,
    float* __restrict__ out)
{
    __shared__ __half resM[RESSZ];               // 17.2 KB (group-padded)
    __shared__ __half resA[RESSZ];               // 17.2 KB
    __shared__ unsigned queue[QCAP];             // 1 KB fixup worklist
    __shared__ int qn;

    const int tid  = threadIdx.x;
    const int wave = tid >> 6;
    const int lane = tid & 63;
    const int bx   = blockIdx.x;
    const int n    = bx / NTILES;
    const int tile = bx % NTILES;
    const int t0   = tile * FB;
    const int nt   = min(FB, NFRAMES - t0);
    const float* __restrict__ xb = x + (size_t)n * XLEN;

    if (tid == 0) qn = 0;
    const int K1     = __brev((unsigned)lane) >> 26;               // bitrev6(lane)
    const int p0lane = __brev((unsigned)((64 - K1) & 63)) >> 26;   // partner lane for reg 0
    __syncthreads();   // qn visible

    const int fa0 = 4 * wave;            // wave covers frames fa0..fa0+3
    if (fa0 < nt) {
        // pair metadata (wave-uniform)
        int  fa[2];   fa[0] = fa0;  fa[1] = fa0 + 2;
        bool ex[2], hasB[2], zero[2];
        int  base[2];
        #pragma unroll
        for (int p = 0; p < 2; ++p) {
            ex[p]   = (fa[p] < nt);
            hasB[p] = (fa[p] + 1 < nt);
            base[p] = (t0 + fa[p]) * STRIDE_ - NFFT;
            zero[p] = (base[p] + NFFT <= 0) || (base[p] >= XLEN);
        }

        // ---- shared per-lane constants: one libm sincos; hw stage twiddles
        float sl, cl;
        sincosf(TWO_PI * (float)lane * (1.0f / 1024.0f), &sl, &cl);

        // ---- shared raw loads: 28 chunks cover frames fa0..fa0+3
        //      pair p: a-frame chunk r -> raw[8p+r], b-frame -> raw[8p+r+4]
        const int base0 = base[0];
        float raw[28];
        #pragma unroll
        for (int r = 0; r < 28; ++r) {
            const int pa = base0 + lane + 64 * r;
            raw[r] = (pa >= 0 && pa < XLEN) ? xb[pa] : 0.0f;
        }

        // ---- window by angle-addition: w[r] = .5 - .5cos(theta + r*pi/8)
        constexpr float WC[16] = {   // cos(r*pi/8)
            1.f,  0.92387953251128676f,  0.70710678118654752f,  0.38268343236508977f,
            0.f, -0.38268343236508977f, -0.70710678118654752f, -0.92387953251128676f,
           -1.f, -0.92387953251128676f, -0.70710678118654752f, -0.38268343236508977f,
            0.f,  0.38268343236508977f,  0.70710678118654752f,  0.92387953251128676f };
        constexpr float WS[16] = {   // sin(r*pi/8)
            0.f,  0.38268343236508977f,  0.70710678118654752f,  0.92387953251128676f,
            1.f,  0.92387953251128676f,  0.70710678118654752f,  0.38268343236508977f,
            0.f, -0.38268343236508977f, -0.70710678118654752f, -0.92387953251128676f,
           -1.f, -0.92387953251128676f, -0.70710678118654752f, -0.38268343236508977f };

        float yr[2][16], yi[2][16];
        #pragma unroll
        for (int p = 0; p < 2; ++p) {
            const float hb = hasB[p] ? 1.0f : 0.0f;
            #pragma unroll
            for (int r = 0; r < 16; ++r) {
                const float w = 0.5f - 0.5f * (cl * WC[r] - sl * WS[r]);
                yr[p][r] = raw[8 * p + r] * w;
                yi[p][r] = raw[8 * p + r + 4] * w * hb;
            }
        }

        // ---- step 1: in-lane 16-pt DFT (both pairs, interleaved) ----
        constexpr float TWC[16] = {
            1.f, 1.f, 1.f, 1.f,
            1.f,  0.92387953251128676f,  0.70710678118654752f,  0.38268343236508977f,
            1.f,  0.70710678118654752f,  0.f,                  -0.70710678118654752f,
            1.f,  0.38268343236508977f, -0.70710678118654752f, -0.92387953251128676f };
        constexpr float TWS[16] = {
            0.f, 0.f, 0.f, 0.f,
            0.f, -0.38268343236508977f, -0.70710678118654752f, -0.92387953251128676f,
            0.f, -0.70710678118654752f, -1.f,                  -0.70710678118654752f,
            0.f, -0.92387953251128676f, -0.70710678118654752f,  0.38268343236508977f };
        #pragma unroll
        for (int p = 0; p < 2; ++p) {
            float Ar[16], Ai[16];
            #pragma unroll
            for (int r0 = 0; r0 < 4; ++r0) {
                float q0r = yr[p][r0],      q0i = yi[p][r0];
                float q1r = yr[p][r0 + 4],  q1i = yi[p][r0 + 4];
                float q2r = yr[p][r0 + 8],  q2i = yi[p][r0 + 8];
                float q3r = yr[p][r0 + 12], q3i = yi[p][r0 + 12];
                float t0r = q0r + q2r, t0i = q0i + q2i;
                float t1r = q0r - q2r, t1i = q0i - q2i;
                float t2r = q1r + q3r, t2i = q1i + q3i;
                float t3r = q1i - q3i, t3i = q3r - q1r;   // -i*(q1-q3)
                Ar[4*r0+0] = t0r + t2r; Ai[4*r0+0] = t0i + t2i;
                Ar[4*r0+1] = t1r + t3r; Ai[4*r0+1] = t1i + t3i;
                Ar[4*r0+2] = t0r - t2r; Ai[4*r0+2] = t0i - t2i;
                Ar[4*r0+3] = t1r - t3r; Ai[4*r0+3] = t1i - t3i;
            }
            #pragma unroll
            for (int idx = 0; idx < 16; ++idx) {
                float tr = Ar[idx] * TWC[idx] - Ai[idx] * TWS[idx];
                Ai[idx]  = Ar[idx] * TWS[idx] + Ai[idx] * TWC[idx];
                Ar[idx]  = tr;
            }
            #pragma unroll
            for (int m = 0; m < 4; ++m) {
                float q0r = Ar[m],      q0i = Ai[m];
                float q1r = Ar[4 + m],  q1i = Ai[4 + m];
                float q2r = Ar[8 + m],  q2i = Ai[8 + m];
                float q3r = Ar[12 + m], q3i = Ai[12 + m];
                float t0r = q0r + q2r, t0i = q0i + q2i;
                float t1r = q0r - q2r, t1i = q0i - q2i;
                float t2r = q1r + q3r, t2i = q1i + q3i;
                float t3r = q1i - q3i, t3i = q3r - q1r;
                yr[p][m + 0]  = t0r + t2r; yi[p][m + 0]  = t0i + t2i;
                yr[p][m + 4]  = t1r + t3r; yi[p][m + 4]  = t1i + t3i;
                yr[p][m + 8]  = t0r - t2r; yi[p][m + 8]  = t0i - t2i;
                yr[p][m + 12] = t1r - t3r; yi[p][m + 12] = t1i - t3i;
            }
        }

        // ---- step 2: shared chained twiddle (cl,-sl)^k2, applied to both ----
        {
            const float c1 = cl, s1 = -sl;
            float cc = 1.0f, ssv = 0.0f;
            #pragma unroll
            for (int k2 = 0; k2 < 16; ++k2) {
                #pragma unroll
                for (int p = 0; p < 2; ++p) {
                    float tr  = yr[p][k2] * cc - yi[p][k2] * ssv;
                    yi[p][k2] = yr[p][k2] * ssv + yi[p][k2] * cc;
                    yr[p][k2] = tr;
                }
                float nc = cc * c1 - ssv * s1;
                ssv = cc * s1 + ssv * c1;
                cc = nc;
            }
        }

        // ---- step 3: cross-lane 64-pt DIF radix-2 (shared stage twiddles) ----
        float tc32, ts32; __sincosf(-TWO_PI * (float)(lane & 31) * (1.0f/64.0f), &ts32, &tc32);
        if (!(lane & 32)) { tc32 = 1.0f; ts32 = 0.0f; }
        float tc16, ts16; __sincosf(-TWO_PI * (float)(lane & 15) * (1.0f/32.0f), &ts16, &tc16);
        if (!(lane & 16)) { tc16 = 1.0f; ts16 = 0.0f; }
        float tc8, ts8;   __sincosf(-TWO_PI * (float)(lane & 7)  * (1.0f/16.0f), &ts8,  &tc8);
        if (!(lane & 8))  { tc8 = 1.0f; ts8 = 0.0f; }
        float tc4, ts4;   __sincosf(-TWO_PI * (float)(lane & 3)  * (1.0f/8.0f),  &ts4,  &tc4);
        if (!(lane & 4))  { tc4 = 1.0f; ts4 = 0.0f; }
        float tc2 = 1.0f, ts2 = 0.0f;
        if ((lane & 2) && (lane & 1)) { tc2 = 0.0f; ts2 = -1.0f; }   // W4^1 = -i

        #pragma unroll
        for (int k2 = 0; k2 < 16; ++k2) {
            #pragma unroll
            for (int p = 0; p < 2; ++p) {
                float ar = yr[p][k2], ai = yi[p][k2];
                XSTAGE(32, tc32, ts32);
                XSTAGE(16, tc16, ts16);
                XSTAGE(8,  tc8,  ts8);
                XSTAGE(4,  tc4,  ts4);
                XSTAGE(2,  tc2,  ts2);
                {   // dist 1: no twiddle
                    float br_ = __shfl_xor(ar, 1, 64);
                    float bi_ = __shfl_xor(ai, 1, 64);
                    float dr_ = (lane & 1) ? (br_ - ar) : (ar + br_);
                    float di_ = (lane & 1) ? (bi_ - ai) : (ai + bi_);
                    ar = dr_; ai = di_;
                }
                yr[p][k2] = ar; yi[p][k2] = ai;   // X[k2 + 16*brev6(l)]
            }
        }

        // ---- untangle + mag/angle + fixup queue (per pair) ----
        #pragma unroll
        for (int p = 0; p < 2; ++p) {
            if (!ex[p]) continue;
            const int faP = fa[p], fbP = faP + 1;
            #pragma unroll
            for (int k2 = 0; k2 < 16; ++k2) {
                float prr, pii;
                if (k2 == 0) {
                    prr = __shfl(yr[p][0], p0lane, 64);
                    pii = __shfl(yi[p][0], p0lane, 64);
                } else {
                    prr = __shfl_xor(yr[p][16 - k2], 63, 64);
                    pii = __shfl_xor(yi[p][16 - k2], 63, 64);
                }
                const int f = k2 + 16 * K1;
                if (f <= NFFT / 2) {
                    const float R0 = yr[p][k2], I0 = yi[p][k2];
                    if (zero[p]) {
                        resM[ridx(f, faP)] = __float2half(0.0f);
                        resA[ridx(f, faP)] = __float2half(0.0f);   // atan2(0,0)=0
                    } else {
                        float reA = 0.5f * (R0 + prr), imA = 0.5f * (I0 - pii);
                        resM[ridx(f, faP)] = __float2half(sqrtf(reA * reA + imA * imA));
                        resA[ridx(f, faP)] = __float2half(fast_atan2(imA, reA));
                        if (fabsf(imA) < TAU && reA < TAU) {
                            int qi = atomicAdd(&qn, 1);
                            if (qi < QCAP)
                                queue[qi] = ((unsigned)faP << 16) | (unsigned)f;
                        }
                    }
                    if (hasB[p]) {
                        float reB = 0.5f * (I0 + pii), imB = 0.5f * (prr - R0);
                        resM[ridx(f, fbP)] = __float2half(sqrtf(reB * reB + imB * imB));
                        resA[ridx(f, fbP)] = __float2half(fast_atan2(imB, reB));
                        if (fabsf(imB) < TAU && reB < TAU) {
                            int qi = atomicAdd(&qn, 1);
                            if (qi < QCAP)
                                queue[qi] = ((unsigned)fbP << 16) | (unsigned)f;
                        }
                    }
                }
            }
        }
    }
    __syncthreads();   // all waves' results + queue visible

    // ---- f64 fixup: wave-cooperative dot with the ACTUAL fp32 basis rows ----
    {
        const int nq = min(qn, QCAP);
        for (int qi = wave; qi < nq; qi += TPB / 64) {
            unsigned e = queue[qi];
            int f  = (int)(e & 0xffffu);
            int ft = (int)(e >> 16);
            int base = (t0 + ft) * STRIDE_ - NFFT;
            const float* __restrict__ br = basis + (size_t)f * NFFT;
            const float* __restrict__ bi = basis + (size_t)(CUTOFF_ + f) * NFFT;
            double sr0 = 0.0, si0 = 0.0, sr1 = 0.0, si1 = 0.0;
            #pragma unroll 2
            for (int hh = lane; hh < NFFT; hh += 128) {
                int p0 = base + hh;
                int p1 = p0 + 64;
                if (p0 >= 0 && p0 < XLEN) {
                    double xv = (double)xb[p0];
                    sr0 += xv * (double)br[hh];
                    si0 += xv * (double)bi[hh];
                }
                if (p1 >= 0 && p1 < XLEN) {
                    double xv = (double)xb[p1];
                    sr1 += xv * (double)br[hh + 64];
                    si1 += xv * (double)bi[hh + 64];
                }
            }
            double sr = sr0 + sr1, si = si0 + si1;
            #pragma unroll
            for (int off = 32; off; off >>= 1) {
                sr += __shfl_down(sr, off);
                si += __shfl_down(si, off);
            }
            if (lane == 0) {
                float re = (float)sr, im = (float)si;
                resM[ridx(f, ft)] = __float2half(sqrtf(re * re + im * im));
                resA[ridx(f, ft)] = __float2half(atan2f(im, re));
            }
        }
    }
    __syncthreads();

    // ---- write-out: full 64B lines per f row (16 consecutive t) ----
    const size_t magbase = (size_t)n * CUTOFF_ * NFRAMES;
    const size_t angoff  = (size_t)BATCH_ * CUTOFF_ * NFRAMES;
    for (int idx = tid; idx < CUTOFF_ * FB; idx += TPB) {
        int f  = idx >> 4;        // idx / FB
        int tt = idx & (FB - 1);  // idx % FB
        if (tt < nt) {
            size_t o = magbase + (size_t)f * NFRAMES + (size_t)(t0 + tt);
            out[o]          = __half2float(resM[ridx(f, tt)]);
            out[angoff + o] = __half2float(resA[ridx(f, tt)]);
        }
    }
}

extern "C" void kernel_launch(void* const* d_in, const int* in_sizes, int n_in,
                              void* d_out, int out_size, void* d_ws, size_t ws_size,
                              hipStream_t stream) {
    const float* x     = (const float*)d_in[0];
    const float* basis = (const float*)d_in[1];
    float* out = (float*)d_out;
    dim3 grid(BATCH_ * NTILES);
    dim3 block(TPB);
    stft_fft_kernel<<<grid, block, 0, stream>>>(x, basis, out);
}

// Round 10
// 292.362 us; speedup vs baseline: 1.3083x; 1.3083x over previous
//
#include <hip/hip_runtime.h>
#include <hip/hip_fp16.h>
#include <math.h>

// R15: R13 base (R14's 2-pair/wave TPB=256 reverted: it cut the LDS-capped
// wave ceiling 32->16/CU, occupancy 38->29.5%, dur 223->353. TLP > ILP here).
// Two VALU cuts on top of R13:
//  1) Full-wave epilogue: lanes with f>512 (half the wave) used to idle
//     through the predicated mag/atan2/store. They hold X[f] and receive
//     X[1024-f] — exactly what frame b's bin fo=1024-f needs:
//     reB=0.5*(pii+I0), imB=0.5*(R0-prr) (identical to R13's formula by
//     conjugate symmetry). Branchless select: low lanes emit frame a @ f,
//     high lanes emit frame b @ 1024-f -> ONE mag/atan2/store per lane
//     (was two predicated). Bins 0/512 are self-partnered (lanes 0,1 @ k2=0):
//     imB==0 exactly; side block guarded by compile-time k2==0.
//  2) Step-2 twiddle W^k2 = W4^a * W^b (a,b in 0..3): 4 independent
//     sub-chains, dep depth ~96 -> ~30 cycles.
// Carries (all verified): four-step FFT 1024=16x64 (in-reg 16pt DFT,
// W1024^(l*k2), 6x radix-2 shfl_xor DIF), two-for-one real FFT, 20-chunk
// dedup load, one libm sincos/pair + angle-addition window, group-padded
// conflict-free result staging, zero-frame direct store, fixup predicate
// (|im|<TAU && re<TAU), poly atan2, f64 fixup, fp16 staging.
// x: (32,1,262144) fp32; basis: (1026,1,1024) fp32.
// out: mag (32,513,1029) ++ angle (32,513,1029) fp32 flat.

#define NFFT     1024
#define STRIDE_  256
#define CUTOFF_  513
#define NFRAMES  1029
#define BATCH_   32
#define XLEN     262144
#define FB       16           // frames per block (8 pairs = 8 waves)
#define TPB      512
#define NTILES   65           // ceil(1029/16)
#define RSTRIDE  (FB + 1)     // 17
#define RESSZ    8800         // >= 512*17 + 32*2 + 15
#define QCAP     256          // expected ~25 used/block
#define TAU      0.05f
#define PI_F     3.14159265358979323846f
#define PIH_F    1.57079632679489661923f
#define TWO_PI   6.28318530717958647692f

// Group-padded result index: lane stride across f-groups = 548B = 137 dwords
// == 9 mod 32 -> conflict-free scatter (2 lanes/bank).
__device__ __forceinline__ int ridx(int f, int tt) {
    return f * RSTRIDE + ((f >> 4) << 1) + tt;
}

// Fast atan2: deg-7 minimax atan on [0,1] + quadrant logic. Max err ~1e-5 rad.
// mx==0 -> NaN, but such bins satisfy the queue predicate -> overwritten.
__device__ __forceinline__ float fast_atan2(float y, float x) {
    float ax = fabsf(x), ay = fabsf(y);
    float mx = fmaxf(ax, ay), mn = fminf(ax, ay);
    float a  = mn * __builtin_amdgcn_rcpf(mx);
    float s  = a * a;
    float r  = a * (0.9998660f + s * (-0.3302995f + s * (0.1801410f + s * (-0.0851330f))));
    if (ay > ax) r = PIH_F - r;
    if (x < 0.0f) r = PI_F - r;
    return copysignf(r, y);
}

// One cross-lane DIF radix-2 stage. Low lane: a+b. High lane: (b-a)*W.
#define XSTAGE(DIST, TC, TS) do {                        \
    float br_ = __shfl_xor(ar, DIST, 64);                \
    float bi_ = __shfl_xor(ai, DIST, 64);                \
    float dr_ = (lane & DIST) ? (br_ - ar) : (ar + br_); \
    float di_ = (lane & DIST) ? (bi_ - ai) : (ai + bi_); \
    ar = dr_ * (TC) - di_ * (TS);                        \
    ai = dr_ * (TS) + di_ * (TC);                        \
} while (0)

__global__ __launch_bounds__(TPB, 4) void stft_fft_kernel(
    const float* __restrict__ x, const float* __restrict__ basis,
    float* __restrict__ out)
{
    __shared__ __half resM[RESSZ];               // 17.2 KB (group-padded)
    __shared__ __half resA[RESSZ];               // 17.2 KB
    __shared__ unsigned queue[QCAP];             // 1 KB fixup worklist
    __shared__ int qn;

    const int tid  = threadIdx.x;
    const int wave = tid >> 6;
    const int lane = tid & 63;
    const int bx   = blockIdx.x;
    const int n    = bx / NTILES;
    const int tile = bx % NTILES;
    const int t0   = tile * FB;
    const int nt   = min(FB, NFRAMES - t0);
    const float* __restrict__ xb = x + (size_t)n * XLEN;

    if (tid == 0) qn = 0;
    const int K1     = __brev((unsigned)lane) >> 26;               // bitrev6(lane)
    const int p0lane = __brev((unsigned)((64 - K1) & 63)) >> 26;   // partner lane for reg 0
    __syncthreads();   // qn visible

    const int fa = 2 * wave;
    if (fa < nt) {
        const int fbv   = fa + 1;
        const bool hasB = (fbv < nt);
        const int baseA = (t0 + fa) * STRIDE_ - NFFT;
        const bool zeroA = (baseA + NFFT <= 0) || (baseA >= XLEN);

        if (zeroA && !hasB) {
            // lone fully-OOB frame (1028): exact zeros, no FFT, no queue
            #pragma unroll
            for (int k2 = 0; k2 < 16; ++k2) {
                const int f = k2 + 16 * K1;
                if (f <= NFFT / 2) {
                    resM[ridx(f, fa)] = __float2half(0.0f);
                    resA[ridx(f, fa)] = __float2half(0.0f);
                }
            }
        } else {
            // ---- one libm sincos per pair: theta = 2*pi*lane/1024 ----
            float sl, cl;
            sincosf(TWO_PI * (float)lane * (1.0f / 1024.0f), &sl, &cl);

            // ---- raw loads: 20 chunks cover frame a (r=0..15) AND frame b
            //      (b's chunk r = a's chunk r+4; 4 extra chunks r=16..19) ----
            float raw[20];
            #pragma unroll
            for (int r = 0; r < 20; ++r) {
                const int pa = baseA + lane + 64 * r;
                raw[r] = (pa >= 0 && pa < XLEN) ? xb[pa] : 0.0f;
            }

            // ---- window by angle-addition: w[r] = .5 - .5cos(theta + r*pi/8)
            constexpr float WC[16] = {   // cos(r*pi/8)
                1.f,  0.92387953251128676f,  0.70710678118654752f,  0.38268343236508977f,
                0.f, -0.38268343236508977f, -0.70710678118654752f, -0.92387953251128676f,
               -1.f, -0.92387953251128676f, -0.70710678118654752f, -0.38268343236508977f,
                0.f,  0.38268343236508977f,  0.70710678118654752f,  0.92387953251128676f };
            constexpr float WS[16] = {   // sin(r*pi/8)
                0.f,  0.38268343236508977f,  0.70710678118654752f,  0.92387953251128676f,
                1.f,  0.92387953251128676f,  0.70710678118654752f,  0.38268343236508977f,
                0.f, -0.38268343236508977f, -0.70710678118654752f, -0.92387953251128676f,
               -1.f, -0.92387953251128676f, -0.70710678118654752f, -0.38268343236508977f };
            const float hb = hasB ? 1.0f : 0.0f;
            float yr[16], yi[16];
            #pragma unroll
            for (int r = 0; r < 16; ++r) {
                const float w = 0.5f - 0.5f * (cl * WC[r] - sl * WS[r]);
                yr[r] = raw[r] * w;
                yi[r] = raw[r + 4] * w * hb;
            }

            // ---- step 1: in-lane 16-pt DFT, y_l[k2] = sum_r x_r W16^{r k2} ----
            float Ar[16], Ai[16];
            #pragma unroll
            for (int r0 = 0; r0 < 4; ++r0) {   // 4-pt DFT over r1 for each r0
                float q0r = yr[r0],      q0i = yi[r0];
                float q1r = yr[r0 + 4],  q1i = yi[r0 + 4];
                float q2r = yr[r0 + 8],  q2i = yi[r0 + 8];
                float q3r = yr[r0 + 12], q3i = yi[r0 + 12];
                float t0r = q0r + q2r, t0i = q0i + q2i;
                float t1r = q0r - q2r, t1i = q0i - q2i;
                float t2r = q1r + q3r, t2i = q1i + q3i;
                float t3r = q1i - q3i, t3i = q3r - q1r;   // -i*(q1-q3)
                Ar[4*r0+0] = t0r + t2r; Ai[4*r0+0] = t0i + t2i;
                Ar[4*r0+1] = t1r + t3r; Ai[4*r0+1] = t1i + t3i;
                Ar[4*r0+2] = t0r - t2r; Ai[4*r0+2] = t0i - t2i;
                Ar[4*r0+3] = t1r - t3r; Ai[4*r0+3] = t1i - t3i;
            }
            // W16^{r0*m} twiddle (compile-time constants), A indexed [4*r0+m]
            constexpr float TWC[16] = {
                1.f, 1.f, 1.f, 1.f,
                1.f,  0.92387953251128676f,  0.70710678118654752f,  0.38268343236508977f,
                1.f,  0.70710678118654752f,  0.f,                  -0.70710678118654752f,
                1.f,  0.38268343236508977f, -0.70710678118654752f, -0.92387953251128676f };
            constexpr float TWS[16] = {
                0.f, 0.f, 0.f, 0.f,
                0.f, -0.38268343236508977f, -0.70710678118654752f, -0.92387953251128676f,
                0.f, -0.70710678118654752f, -1.f,                  -0.70710678118654752f,
                0.f, -0.92387953251128676f, -0.70710678118654752f,  0.38268343236508977f };
            #pragma unroll
            for (int idx = 0; idx < 16; ++idx) {
                float tr = Ar[idx] * TWC[idx] - Ai[idx] * TWS[idx];
                Ai[idx]  = Ar[idx] * TWS[idx] + Ai[idx] * TWC[idx];
                Ar[idx]  = tr;
            }
            #pragma unroll
            for (int m = 0; m < 4; ++m) {      // 4-pt DFT over r0, y[m+4p]
                float q0r = Ar[m],      q0i = Ai[m];
                float q1r = Ar[4 + m],  q1i = Ai[4 + m];
                float q2r = Ar[8 + m],  q2i = Ai[8 + m];
                float q3r = Ar[12 + m], q3i = Ai[12 + m];
                float t0r = q0r + q2r, t0i = q0i + q2i;
                float t1r = q0r - q2r, t1i = q0i - q2i;
                float t2r = q1r + q3r, t2i = q1i + q3i;
                float t3r = q1i - q3i, t3i = q3r - q1r;
                yr[m + 0]  = t0r + t2r; yi[m + 0]  = t0i + t2i;
                yr[m + 4]  = t1r + t3r; yi[m + 4]  = t1i + t3i;
                yr[m + 8]  = t0r - t2r; yi[m + 8]  = t0i - t2i;
                yr[m + 12] = t1r - t3r; yi[m + 12] = t1i - t3i;
            }

            // ---- step 2: W^k2 = W4^a * W^b (a,b in 0..3): 4 independent
            //      sub-chains (dep depth ~30 vs 96 for the serial recurrence)
            {
                const float w1c = cl,  w1s = -sl;
                const float w2c = w1c * w1c - w1s * w1s, w2s = 2.0f * w1c * w1s;
                const float w3c = w2c * w1c - w2s * w1s, w3s = w2c * w1s + w2s * w1c;
                const float w4c = w2c * w2c - w2s * w2s, w4s = 2.0f * w2c * w2s;
                const float wbc[4] = {1.0f, w1c, w2c, w3c};
                const float wbs[4] = {0.0f, w1s, w2s, w3s};
                float bc = 1.0f, bs = 0.0f;   // W4^a
                #pragma unroll
                for (int a = 0; a < 4; ++a) {
                    #pragma unroll
                    for (int b = 0; b < 4; ++b) {
                        const int k2 = 4 * a + b;
                        float twc = bc * wbc[b] - bs * wbs[b];
                        float tws = bc * wbs[b] + bs * wbc[b];
                        float tr  = yr[k2] * twc - yi[k2] * tws;
                        yi[k2]    = yr[k2] * tws + yi[k2] * twc;
                        yr[k2]    = tr;
                    }
                    float nbc = bc * w4c - bs * w4s;
                    bs = bc * w4s + bs * w4c;
                    bc = nbc;
                }
            }

            // ---- step 3: cross-lane 64-pt DIF radix-2, stage twiddles (hw) ----
            float tc32, ts32; __sincosf(-TWO_PI * (float)(lane & 31) * (1.0f/64.0f), &ts32, &tc32);
            if (!(lane & 32)) { tc32 = 1.0f; ts32 = 0.0f; }
            float tc16, ts16; __sincosf(-TWO_PI * (float)(lane & 15) * (1.0f/32.0f), &ts16, &tc16);
            if (!(lane & 16)) { tc16 = 1.0f; ts16 = 0.0f; }
            float tc8, ts8;   __sincosf(-TWO_PI * (float)(lane & 7)  * (1.0f/16.0f), &ts8,  &tc8);
            if (!(lane & 8))  { tc8 = 1.0f; ts8 = 0.0f; }
            float tc4, ts4;   __sincosf(-TWO_PI * (float)(lane & 3)  * (1.0f/8.0f),  &ts4,  &tc4);
            if (!(lane & 4))  { tc4 = 1.0f; ts4 = 0.0f; }
            float tc2 = 1.0f, ts2 = 0.0f;
            if ((lane & 2) && (lane & 1)) { tc2 = 0.0f; ts2 = -1.0f; }   // W4^1 = -i

            #pragma unroll
            for (int k2 = 0; k2 < 16; ++k2) {
                float ar = yr[k2], ai = yi[k2];
                XSTAGE(32, tc32, ts32);
                XSTAGE(16, tc16, ts16);
                XSTAGE(8,  tc8,  ts8);
                XSTAGE(4,  tc4,  ts4);
                XSTAGE(2,  tc2,  ts2);
                {   // dist 1: no twiddle
                    float br_ = __shfl_xor(ar, 1, 64);
                    float bi_ = __shfl_xor(ai, 1, 64);
                    float dr_ = (lane & 1) ? (br_ - ar) : (ar + br_);
                    float di_ = (lane & 1) ? (bi_ - ai) : (ai + bi_);
                    ar = dr_; ai = di_;
                }
                yr[k2] = ar; yi[k2] = ai;   // lane l, reg k2 = X[k2 + 16*brev6(l)]
            }

            // ---- full-wave epilogue: low lanes (f<=512) emit frame a @ f;
            //      high lanes emit frame b @ 1024-f. One mag/atan2/store per
            //      lane. Bins 0/512 self-partnered: B emitted in k2==0 block.
            #pragma unroll
            for (int k2 = 0; k2 < 16; ++k2) {
                float prr, pii;
                if (k2 == 0) {
                    prr = __shfl(yr[0], p0lane, 64);
                    pii = __shfl(yi[0], p0lane, 64);
                } else {
                    prr = __shfl_xor(yr[16 - k2], 63, 64);
                    pii = __shfl_xor(yi[16 - k2], 63, 64);
                }
                const int f    = k2 + 16 * K1;
                const bool low = (f <= NFFT / 2);
                const float R0 = yr[k2], I0 = yi[k2];
                // branchless operand select
                const float re = low ? 0.5f * (R0 + prr) : 0.5f * (pii + I0);
                const float im = low ? 0.5f * (I0 - pii) : 0.5f * (R0 - prr);
                const int  fo  = low ? f : NFFT - f;
                const int  ftt = low ? fa : fbv;
                const bool emit = low || hasB;

                if (zeroA && low) {
                    resM[ridx(f, fa)] = __float2half(0.0f);
                    resA[ridx(f, fa)] = __float2half(0.0f);   // atan2(0,0)=0
                } else if (emit) {
                    resM[ridx(fo, ftt)] = __float2half(sqrtf(re * re + im * im));
                    resA[ridx(fo, ftt)] = __float2half(fast_atan2(im, re));
                    if (fabsf(im) < TAU && re < TAU) {
                        int qi = atomicAdd(&qn, 1);
                        if (qi < QCAP)
                            queue[qi] = ((unsigned)ftt << 16) | (unsigned)fo;
                    }
                }

                // self-partnered bins (f==0 lane 0, f==512 lane 1; only k2==0):
                // frame b there: reB = I0 (pii==I0), imB = 0 exactly.
                if (k2 == 0 && hasB && (f == 0 || f == NFFT / 2)) {
                    const float reB = I0;
                    resM[ridx(f, fbv)] = __float2half(fabsf(reB));
                    resA[ridx(f, fbv)] = __float2half(reB < 0.0f ? PI_F : 0.0f);
                    if (reB < TAU) {
                        int qi = atomicAdd(&qn, 1);
                        if (qi < QCAP)
                            queue[qi] = ((unsigned)fbv << 16) | (unsigned)f;
                    }
                }
            }
        }
    }
    __syncthreads();   // all waves' results + queue visible

    // ---- f64 fixup: wave-cooperative dot with the ACTUAL fp32 basis rows ----
    {
        const int nq = min(qn, QCAP);
        for (int qi = wave; qi < nq; qi += TPB / 64) {
            unsigned e = queue[qi];
            int f  = (int)(e & 0xffffu);
            int ft = (int)(e >> 16);
            int base = (t0 + ft) * STRIDE_ - NFFT;
            const float* __restrict__ br = basis + (size_t)f * NFFT;
            const float* __restrict__ bi = basis + (size_t)(CUTOFF_ + f) * NFFT;
            double sr0 = 0.0, si0 = 0.0, sr1 = 0.0, si1 = 0.0;
            #pragma unroll 2
            for (int hh = lane; hh < NFFT; hh += 128) {
                int p0 = base + hh;
                int p1 = p0 + 64;
                if (p0 >= 0 && p0 < XLEN) {
                    double xv = (double)xb[p0];
                    sr0 += xv * (double)br[hh];
                    si0 += xv * (double)bi[hh];
                }
                if (p1 >= 0 && p1 < XLEN) {
                    double xv = (double)xb[p1];
                    sr1 += xv * (double)br[hh + 64];
                    si1 += xv * (double)bi[hh + 64];
                }
            }
            double sr = sr0 + sr1, si = si0 + si1;
            #pragma unroll
            for (int off = 32; off; off >>= 1) {
                sr += __shfl_down(sr, off);
                si += __shfl_down(si, off);
            }
            if (lane == 0) {
                float re = (float)sr, im = (float)si;
                resM[ridx(f, ft)] = __float2half(sqrtf(re * re + im * im));
                resA[ridx(f, ft)] = __float2half(atan2f(im, re));
            }
        }
    }
    __syncthreads();

    // ---- write-out: full 64B lines per f row (16 consecutive t) ----
    const size_t magbase = (size_t)n * CUTOFF_ * NFRAMES;
    const size_t angoff  = (size_t)BATCH_ * CUTOFF_ * NFRAMES;
    for (int idx = tid; idx < CUTOFF_ * FB; idx += TPB) {
        int f  = idx >> 4;        // idx / FB
        int tt = idx & (FB - 1);  // idx % FB
        if (tt < nt) {
            size_t o = magbase + (size_t)f * NFRAMES + (size_t)(t0 + tt);
            out[o]          = __half2float(resM[ridx(f, tt)]);
            out[angoff + o] = __half2float(resA[ridx(f, tt)]);
        }
    }
}

extern "C" void kernel_launch(void* const* d_in, const int* in_sizes, int n_in,
                              void* d_out, int out_size, void* d_ws, size_t ws_size,
                              hipStream_t stream) {
    const float* x     = (const float*)d_in[0];
    const float* basis = (const float*)d_in[1];
    float* out = (float*)d_out;
    dim3 grid(BATCH_ * NTILES);
    dim3 block(TPB);
    stft_fft_kernel<<<grid, block, 0, stream>>>(x, basis, out);
}